// Round 3
// baseline (124.973 us; speedup 1.0000x reference)
//
#include <hip/hip_runtime.h>

#define N_NODES 131072
#define C_IN 32
#define C_OUT 32
#define KTAPS 27
#define BN_EPS 1e-5f
#define NPASS 3

typedef __bf16 bf16x8 __attribute__((ext_vector_type(8)));
typedef float  f32x4  __attribute__((ext_vector_type(4)));

// ws layout:
//   xb   : (N_NODES+1) rows x 32 bf16  (row N_NODES = zeros, gather dummy target)
//   wlay : 27 taps x 2 co-halves x 64 lanes x 8 bf16  (55296 B)
//   sums : 32 sum + 32 sumsq (f32)

static __device__ __forceinline__ unsigned short f2bf(float f) {
    unsigned int u = __float_as_uint(f);
    unsigned int r = (u + 0x7FFFu + ((u >> 16) & 1u)) >> 16;  // RNE
    return (unsigned short)r;
}

// ---- prep: x transpose -> node-major bf16; block 0 also builds wlay + zero row ----
__global__ __launch_bounds__(256) void k_prep(const float* __restrict__ in,
                                              const float* __restrict__ w,
                                              unsigned short* __restrict__ xb,
                                              unsigned short* __restrict__ wlay) {
    const int n = blockIdx.x * 256 + threadIdx.x;
    unsigned short v[C_IN];
#pragma unroll
    for (int c = 0; c < C_IN; ++c) v[c] = f2bf(in[(size_t)c * N_NODES + n]);
    uint4* dst = reinterpret_cast<uint4*>(xb + (size_t)n * C_IN);
#pragma unroll
    for (int q = 0; q < 4; ++q) {
        uint4 pk;
        pk.x = (unsigned)v[q * 8 + 0] | ((unsigned)v[q * 8 + 1] << 16);
        pk.y = (unsigned)v[q * 8 + 2] | ((unsigned)v[q * 8 + 3] << 16);
        pk.z = (unsigned)v[q * 8 + 4] | ((unsigned)v[q * 8 + 5] << 16);
        pk.w = (unsigned)v[q * 8 + 6] | ((unsigned)v[q * 8 + 7] << 16);
        dst[q] = pk;
    }
    if (blockIdx.x == 0) {
        // zero row at index N_NODES
        if (threadIdx.x < 4) {
            uint4 z = {0u, 0u, 0u, 0u};
            reinterpret_cast<uint4*>(xb + (size_t)N_NODES * C_IN)[threadIdx.x] = z;
        }
        // weight relayout: one 8-bf16 frag per iteration
        for (int g = threadIdx.x; g < KTAPS * 2 * 64; g += 256) {
            const int k = g >> 7;
            const int rem = g & 127;
            const int h = rem >> 6;
            const int l = rem & 63;
            unsigned short wv[8];
#pragma unroll
            for (int j = 0; j < 8; ++j) {
                const int c  = ((l >> 4) << 3) + j;
                const int co = (h << 4) + (l & 15);
                wv[j] = f2bf(w[(size_t)(k * C_IN + c) * C_OUT + co]);
            }
            uint4 pk;
            pk.x = (unsigned)wv[0] | ((unsigned)wv[1] << 16);
            pk.y = (unsigned)wv[2] | ((unsigned)wv[3] << 16);
            pk.z = (unsigned)wv[4] | ((unsigned)wv[5] << 16);
            pk.w = (unsigned)wv[6] | ((unsigned)wv[7] << 16);
            *reinterpret_cast<uint4*>(wlay + (size_t)g * 8) = pk;
        }
    }
}

// ---- conv: 3-pass L2-resident gather, weights in LDS, 4 waves x 4 groups x 16 nodes ----
__global__ __launch_bounds__(256, 2) void k_conv_mfma(const unsigned short* __restrict__ xb,
                                                      const int* __restrict__ neigh,
                                                      const unsigned short* __restrict__ wlay,
                                                      float* __restrict__ out) {
    __shared__ unsigned short wl[KTAPS * 2 * 64 * 8];  // 55296 B

    {   // cooperative stage: 3456 uint4
        const uint4* src = reinterpret_cast<const uint4*>(wlay);
        uint4* d = reinterpret_cast<uint4*>(wl);
        for (int i = threadIdx.x; i < KTAPS * 2 * 64; i += 256) d[i] = src[i];
    }
    __syncthreads();

    const int wid  = threadIdx.x >> 6;
    const int lane = threadIdx.x & 63;
    const int lr   = lane & 15;   // node offset within group (B/D col)
    const int lg   = lane >> 4;   // k-group (channel slice)
    const int nb   = blockIdx.x * 256 + wid * 64;  // wave's 64 nodes

    f32x4 acc[4][2];
#pragma unroll
    for (int g = 0; g < 4; ++g) {
        acc[g][0] = (f32x4){0.f, 0.f, 0.f, 0.f};
        acc[g][1] = (f32x4){0.f, 0.f, 0.f, 0.f};
    }

    for (int p = 0; p < NPASS; ++p) {
        const int lo = (p * N_NODES) / NPASS;
        const int hi = ((p + 1) * N_NODES) / NPASS;
        for (int k = 0; k < KTAPS; ++k) {
            const bf16x8 w0 = *reinterpret_cast<const bf16x8*>(wl + ((size_t)(k * 2 + 0) * 64 + lane) * 8);
            const bf16x8 w1 = *reinterpret_cast<const bf16x8*>(wl + ((size_t)(k * 2 + 1) * 64 + lane) * 8);
#pragma unroll
            for (int g = 0; g < 4; ++g) {
                const int idx = neigh[(size_t)(nb + g * 16 + lr) * KTAPS + k];
                const bool valid = (idx >= lo) && (idx < hi);
                const int src = valid ? idx : N_NODES;  // zero row -> contributes 0
                const bf16x8 xf = *reinterpret_cast<const bf16x8*>(xb + (size_t)src * C_IN + lg * 8);
                acc[g][0] = __builtin_amdgcn_mfma_f32_16x16x32_bf16(w0, xf, acc[g][0], 0, 0, 0);
                acc[g][1] = __builtin_amdgcn_mfma_f32_16x16x32_bf16(w1, xf, acc[g][1], 0, 0, 0);
            }
        }
    }

    // D layout: col = lane&15 -> node, row = lg*4 + r -> c_out
#pragma unroll
    for (int g = 0; g < 4; ++g)
#pragma unroll
        for (int r = 0; r < 4; ++r) {
            out[(size_t)(lg * 4 + r) * N_NODES + nb + g * 16 + lr]      = acc[g][0][r];
            out[(size_t)(16 + lg * 4 + r) * N_NODES + nb + g * 16 + lr] = acc[g][1][r];
        }
}

// ---- BN stats over pre-BN out (channel-major, coalesced) ----
__global__ __launch_bounds__(256) void k_stats(const float* __restrict__ out,
                                               float* __restrict__ sums) {
    const int c     = blockIdx.x >> 3;
    const int chunk = blockIdx.x & 7;
    const float4* base = reinterpret_cast<const float4*>(out + (size_t)c * N_NODES + chunk * (N_NODES / 8));
    float s = 0.f, s2 = 0.f;
    for (int i = threadIdx.x; i < N_NODES / 8 / 4; i += 256) {
        float4 v = base[i];
        s  += v.x + v.y + v.z + v.w;
        s2 += v.x * v.x + v.y * v.y + v.z * v.z + v.w * v.w;
    }
#pragma unroll
    for (int off = 32; off >= 1; off >>= 1) {
        s  += __shfl_xor(s,  off);
        s2 += __shfl_xor(s2, off);
    }
    __shared__ float ls[8];
    const int wid = threadIdx.x >> 6;
    if ((threadIdx.x & 63) == 0) { ls[wid * 2] = s; ls[wid * 2 + 1] = s2; }
    __syncthreads();
    if (threadIdx.x == 0) {
        float ts  = ls[0] + ls[2] + ls[4] + ls[6];
        float ts2 = ls[1] + ls[3] + ls[5] + ls[7];
        atomicAdd(&sums[c], ts);
        atomicAdd(&sums[C_OUT + c], ts2);
    }
}

// ---- BN + ReLU in-place ----
__global__ __launch_bounds__(256) void k_bnrelu(float* __restrict__ out,
                                                const float* __restrict__ sums,
                                                const float* __restrict__ gamma,
                                                const float* __restrict__ beta) {
    const size_t gid = (size_t)blockIdx.x * 256 + threadIdx.x;  // over float4s
    const int co = (int)(gid / (N_NODES / 4));
    const float inv_n = 1.0f / (float)N_NODES;
    const float mean = sums[co] * inv_n;
    const float var  = sums[C_OUT + co] * inv_n - mean * mean;
    const float scale = rsqrtf(var + BN_EPS) * gamma[co];
    const float bias  = beta[co] - mean * scale;

    float4* p = reinterpret_cast<float4*>(out);
    float4 v = p[gid];
    v.x = fmaxf(fmaf(v.x, scale, bias), 0.0f);
    v.y = fmaxf(fmaf(v.y, scale, bias), 0.0f);
    v.z = fmaxf(fmaf(v.z, scale, bias), 0.0f);
    v.w = fmaxf(fmaf(v.w, scale, bias), 0.0f);
    p[gid] = v;
}

extern "C" void kernel_launch(void* const* d_in, const int* in_sizes, int n_in,
                              void* d_out, int out_size, void* d_ws, size_t ws_size,
                              hipStream_t stream) {
    const float* data_in = (const float*)d_in[0];
    const int*   neigh   = (const int*)d_in[1];
    const float* weight  = (const float*)d_in[2];
    const float* gamma   = (const float*)d_in[3];
    const float* beta    = (const float*)d_in[4];
    float* out = (float*)d_out;

    unsigned short* xb   = (unsigned short*)d_ws;                        // (N+1)*32 bf16
    unsigned short* wlay = xb + (size_t)(N_NODES + 1) * C_IN;            // 55296 B
    float* sums = (float*)(wlay + (size_t)KTAPS * 2 * 64 * 8);           // 64 f32

    hipMemsetAsync(sums, 0, 2 * C_OUT * sizeof(float), stream);
    k_prep<<<N_NODES / 256, 256, 0, stream>>>(data_in, weight, xb, wlay);
    k_conv_mfma<<<N_NODES / 256, 256, 0, stream>>>(xb, neigh, wlay, out);
    k_stats<<<C_OUT * 8, 256, 0, stream>>>(out, sums);
    k_bnrelu<<<(N_NODES * C_OUT / 4) / 256, 256, 0, stream>>>(out, sums, gamma, beta);
}